// Round 1
// baseline (245.609 us; speedup 1.0000x reference)
//
#include <hip/hip_runtime.h>
#include <stdint.h>
#include <stddef.h>

// RadialCTC: cosine logits (norm_scale=32) -> log_softmax -> CTC(sum).
// Strategy: never materialize the (16384 x 1296) logits. GEMM (f16 MFMA)
// computes per-row sum(exp(logit)) fused in the epilogue (no max needed:
// logits in [-32,32]); label log-probs recomputed by a tiny gather kernel;
// CTC alpha recursion runs one wave per sample with shfl_up.

typedef _Float16 f16;
typedef _Float16 f16x8 __attribute__((ext_vector_type(8)));
typedef float f32x4 __attribute__((ext_vector_type(4)));
typedef __attribute__((address_space(1))) void* as1_void_ptr;
typedef __attribute__((address_space(3))) void* as3_void_ptr;

#define TT 512
#define NN 32
#define CC 1296
#define DD 512
#define SS 30
#define CP 1408   // C padded to 11*128 for GEMM tiling (pad rows are zero)
#define LL 61     // 2*S+1 CTC states
#define NEGINF (-1e9f)
#define NORM_SCALE 32.0f

// ---- col sum-of-squares of W (D x C), partial over d-chunks, atomic ----
__global__ void colnorm_kernel(const float* __restrict__ W, float* __restrict__ ssq) {
    int c = blockIdx.x * 64 + threadIdx.x;
    if (c >= CC) return;
    int d0 = blockIdx.y * 64;
    float ss = 0.f;
    #pragma unroll 8
    for (int d = d0; d < d0 + 64; ++d) {
        float v = W[(size_t)d * CC + c];
        ss += v * v;
    }
    atomicAdd(&ssq[c], ss);
}

// ---- build padded transposed normalized weight w_t (CP x DD), f16 ----
__global__ void wt_kernel(const float* __restrict__ W, const float* __restrict__ ssq,
                          f16* __restrict__ wt) {
    int idx = blockIdx.x * 256 + threadIdx.x;   // idx < CP*DD
    int c = idx >> 9, d = idx & 511;
    float v = 0.f;
    if (c < CC) v = W[(size_t)d * CC + c] * rsqrtf(ssq[c]);
    wt[idx] = (f16)v;
}

// ---- feats row-normalize -> f16 (one wave per row) ----
__global__ __launch_bounds__(256) void fnorm_kernel(const float* __restrict__ feats,
                                                    f16* __restrict__ fn) {
    int wv = (blockIdx.x * 256 + threadIdx.x) >> 6;  // row id, 0..16383
    int lane = threadIdx.x & 63;
    const float4* src = (const float4*)(feats + (size_t)wv * DD) + lane * 2;
    float4 a = src[0], b = src[1];
    float ss = a.x*a.x + a.y*a.y + a.z*a.z + a.w*a.w
             + b.x*b.x + b.y*b.y + b.z*b.z + b.w*b.w;
    #pragma unroll
    for (int off = 32; off; off >>= 1) ss += __shfl_xor(ss, off);
    float r = rsqrtf(ss);
    f16x8 o;
    o[0]=(f16)(a.x*r); o[1]=(f16)(a.y*r); o[2]=(f16)(a.z*r); o[3]=(f16)(a.w*r);
    o[4]=(f16)(b.x*r); o[5]=(f16)(b.y*r); o[6]=(f16)(b.z*r); o[7]=(f16)(b.w*r);
    *(f16x8*)(fn + (size_t)wv * DD + lane * 8) = o;
}

// ---- MFMA GEMM (A: 16384x512 f16, B^T: 1408x512 f16) with fused
//      row-wise sum(exp(32*dot)) epilogue -> atomicAdd into sumexp[16384] ----
__global__ __launch_bounds__(256) void gemm_sumexp_kernel(const f16* __restrict__ A,
                                                          const f16* __restrict__ B,
                                                          float* __restrict__ sumexp) {
    __shared__ __align__(16) f16 As[128 * 32];
    __shared__ __align__(16) f16 Bs[128 * 32];
    int bm = blockIdx.x, bn = blockIdx.y;
    int tid = threadIdx.x;
    int w = tid >> 6, lane = tid & 63;
    int wm = w >> 1, wn = w & 1;           // 2x2 wave grid -> 64x64 per wave
    int lm = lane & 15, hi = lane >> 4;
    f32x4 acc[4][4];
    f32x4 zero = {0.f, 0.f, 0.f, 0.f};
    #pragma unroll
    for (int i = 0; i < 4; ++i)
        #pragma unroll
        for (int j = 0; j < 4; ++j) acc[i][j] = zero;

    for (int kb = 0; kb < 16; ++kb) {      // K=512, BK=32 (one MFMA K-step)
        #pragma unroll
        for (int p = 0; p < 2; ++p) {
            int s = p * 256 + tid;         // segment id, 16B each; 512 segs/tile
            int row = s >> 2, ch = s & 3;
            const f16* ga = A + (size_t)(bm * 128 + row) * DD + kb * 32 + ch * 8;
            const f16* gb = B + (size_t)(bn * 128 + row) * DD + kb * 32 + ch * 8;
            // LDS dest = wave-uniform base + lane*16
            __builtin_amdgcn_global_load_lds((as1_void_ptr)ga,
                (as3_void_ptr)&As[(p * 256 + w * 64) * 8], 16, 0, 0);
            __builtin_amdgcn_global_load_lds((as1_void_ptr)gb,
                (as3_void_ptr)&Bs[(p * 256 + w * 64) * 8], 16, 0, 0);
        }
        __syncthreads();
        f16x8 af[4], bf[4];
        #pragma unroll
        for (int i = 0; i < 4; ++i)
            af[i] = *(const f16x8*)&As[(wm * 64 + i * 16 + lm) * 32 + hi * 8];
        #pragma unroll
        for (int j = 0; j < 4; ++j)
            bf[j] = *(const f16x8*)&Bs[(wn * 64 + j * 16 + lm) * 32 + hi * 8];
        #pragma unroll
        for (int i = 0; i < 4; ++i)
            #pragma unroll
            for (int j = 0; j < 4; ++j)
                acc[i][j] = __builtin_amdgcn_mfma_f32_16x16x32_f16(af[i], bf[j], acc[i][j], 0, 0, 0);
        __syncthreads();
    }
    // epilogue: per-row sum of exp(32*logit) over this block's 128 columns
    #pragma unroll
    for (int i = 0; i < 4; ++i) {
        float rs[4] = {0.f, 0.f, 0.f, 0.f};
        #pragma unroll
        for (int j = 0; j < 4; ++j) {
            int c = bn * 128 + wn * 64 + j * 16 + lm;   // C/D: col = lane&15
            bool ok = (c < CC);
            #pragma unroll
            for (int r = 0; r < 4; ++r)
                rs[r] += ok ? __expf(acc[i][j][r] * NORM_SCALE) : 0.f;
        }
        #pragma unroll
        for (int off = 1; off < 16; off <<= 1) {        // sum over 16 cols
            #pragma unroll
            for (int r = 0; r < 4; ++r) rs[r] += __shfl_xor(rs[r], off);
        }
        if (lm == 0) {
            int rowb = bm * 128 + wm * 64 + i * 16 + hi * 4;  // row = quad*4+reg
            #pragma unroll
            for (int r = 0; r < 4; ++r) atomicAdd(&sumexp[rowb + r], rs[r]);
        }
    }
}

// ---- gather: lp_lab[n][t][j] = 32*dot(f_n[row], w_t[cls_j]) - log(sumexp[row]) ----
__global__ __launch_bounds__(256) void gather_kernel(const f16* __restrict__ fn,
                                                     const f16* __restrict__ wt,
                                                     const float* __restrict__ sumexp,
                                                     const int* __restrict__ labels,
                                                     float* __restrict__ lp_lab) {
    int wv = (blockIdx.x * 256 + threadIdx.x) >> 6;  // row = t*32+n
    int lane = threadIdx.x & 63;
    int t = wv >> 5, n = wv & 31;
    f16x8 f8 = *(const f16x8*)(fn + (size_t)wv * DD + lane * 8);
    float fv[8];
    #pragma unroll
    for (int k = 0; k < 8; ++k) fv[k] = (float)f8[k];
    float lse = __logf(sumexp[wv]);
    float myval = 0.f;
    for (int j = 0; j < 31; ++j) {
        int cls = (j == 0) ? 0 : labels[n * SS + j - 1];
        f16x8 w8 = *(const f16x8*)(wt + (size_t)cls * DD + lane * 8);
        float d = 0.f;
        #pragma unroll
        for (int k = 0; k < 8; ++k) d += fv[k] * (float)w8[k];
        #pragma unroll
        for (int off = 32; off; off >>= 1) d += __shfl_xor(d, off);
        if (lane == j) myval = d;
    }
    if (lane < 31)
        lp_lab[((size_t)n * TT + t) * 31 + lane] = NORM_SCALE * myval - lse;
}

// ---- CTC alpha recursion: one wave per sample, lane = state ----
__global__ void ctc_kernel(const float* __restrict__ lp_lab, const int* __restrict__ labels,
                           const int* __restrict__ in_lens, const int* __restrict__ lab_lens,
                           float* __restrict__ nll) {
    int n = blockIdx.x;
    int s = threadIdx.x;     // 64 lanes; states 0..60 valid
    int ext = 0;
    if (s < LL && (s & 1)) ext = labels[n * SS + (s >> 1)];
    int jmap = (s & 1) ? ((s >> 1) + 1) : 0;   // state -> class slot in lp_lab
    int ext2 = __shfl_up(ext, 2);
    bool skip = (s >= 2) && (s < LL) && (ext != ext2);
    const float* lpn = lp_lab + (size_t)n * TT * 31;
    float lp0 = (s < LL) ? lpn[jmap] : NEGINF;
    float alpha = (s <= 1) ? lp0 : NEGINF;
    int Tin = in_lens[n];
    float lp_next = (s < LL) ? lpn[31 + jmap] : NEGINF;
    for (int t = 1; t < TT; ++t) {
        float lp = lp_next;
        if (t + 1 < TT) lp_next = (s < LL) ? lpn[(t + 1) * 31 + jmap] : NEGINF;
        float a1 = alpha;
        float a2 = __shfl_up(alpha, 1); if (s < 1) a2 = NEGINF;
        float a3 = __shfl_up(alpha, 2); if (!skip) a3 = NEGINF;
        float m = fmaxf(a1, fmaxf(a2, a3));
        float nv = m + __logf(__expf(a1 - m) + __expf(a2 - m) + __expf(a3 - m)) + lp;
        if (t < Tin) alpha = nv;   // freeze past input length
    }
    int Ln = 2 * lab_lens[n] + 1;
    float last  = __shfl(alpha, Ln - 1);
    float last2 = __shfl(alpha, Ln - 2);
    float m2 = fmaxf(last, last2);
    float v = -(m2 + __logf(__expf(last - m2) + __expf(last2 - m2)));
    if (s == 0) nll[n] = v;
}

__global__ void reduce_kernel(const float* __restrict__ nll, float* __restrict__ out) {
    int s = threadIdx.x;
    float v = (s < NN) ? nll[s] : 0.f;
    #pragma unroll
    for (int off = 32; off; off >>= 1) v += __shfl_xor(v, off);
    if (s == 0) out[0] = v;
}

extern "C" void kernel_launch(void* const* d_in, const int* in_sizes, int n_in,
                              void* d_out, int out_size, void* d_ws, size_t ws_size,
                              hipStream_t stream) {
    const float* feats        = (const float*)d_in[0];
    const float* W            = (const float*)d_in[1];
    const int*   labeling     = (const int*)d_in[2];
    const int*   logit_lgts   = (const int*)d_in[3];
    const int*   labeling_lgts= (const int*)d_in[4];
    float* out = (float*)d_out;
    char* ws = (char*)d_ws;

    size_t off = 0;
    f16*   wt     = (f16*)(ws + off);   off += (size_t)CP * DD * 2;        // 1.44 MB
    f16*   fn     = (f16*)(ws + off);   off += (size_t)TT * NN * DD * 2;   // 16.8 MB
    float* ssq    = (float*)(ws + off); off += 1312 * 4;
    float* sumexp = (float*)(ws + off); off += (size_t)TT * NN * 4;        // 64 KB
    float* lp_lab = (float*)(ws + off); off += (size_t)NN * TT * 31 * 4;   // 2.0 MB
    float* nllb   = (float*)(ws + off); off += 64 * 4;

    hipMemsetAsync(ssq, 0, 1312 * 4, stream);
    hipMemsetAsync(sumexp, 0, (size_t)TT * NN * 4, stream);

    colnorm_kernel<<<dim3((CC + 63) / 64, 8), 64, 0, stream>>>(W, ssq);
    wt_kernel<<<(CP * DD) / 256, 256, 0, stream>>>(W, ssq, wt);
    fnorm_kernel<<<(TT * NN) / 4, 256, 0, stream>>>(feats, fn);
    gemm_sumexp_kernel<<<dim3(TT * NN / 128, CP / 128), 256, 0, stream>>>(fn, wt, sumexp);
    gather_kernel<<<(TT * NN) / 4, 256, 0, stream>>>(fn, wt, sumexp, labeling, lp_lab);
    ctc_kernel<<<NN, 64, 0, stream>>>(lp_lab, labeling, logit_lgts, labeling_lgts, nllb);
    reduce_kernel<<<1, 64, 0, stream>>>(nllb, out);

    (void)in_sizes; (void)n_in; (void)out_size; (void)ws_size;
}

// Round 3
// 204.911 us; speedup vs baseline: 1.1986x; 1.1986x over previous
//
#include <hip/hip_runtime.h>
#include <stdint.h>
#include <stddef.h>

// RadialCTC: cosine logits (norm_scale=32) -> log_softmax -> CTC(sum).
// Strategy: never materialize the (16384 x 1296) logits. GEMM (f16 MFMA)
// computes per-row sum(exp(logit)) fused in the epilogue (no max needed:
// logits in [-32,32]); label log-probs recomputed by a tiny gather kernel;
// CTC alpha recursion runs one wave per sample with shfl_up.
// R2: lp_lab transposed to [n][31][T] (float4 feed, 8-step prefetch);
//     CTC recursion in base-2 via __builtin_amdgcn_exp2f/_logf
//     (v_exp_f32 / v_log_f32 are natively base-2; __exp2f/__log2f
//     collide with glibc math.h macros and don't compile).

typedef _Float16 f16;
typedef _Float16 f16x8 __attribute__((ext_vector_type(8)));
typedef float f32x4 __attribute__((ext_vector_type(4)));
typedef __attribute__((address_space(1))) void* as1_void_ptr;
typedef __attribute__((address_space(3))) void* as3_void_ptr;

#define TT 512
#define NN 32
#define CC 1296
#define DD 512
#define SS 30
#define CP 1408   // C padded to 11*128 for GEMM tiling (pad rows are zero)
#define LL 61     // 2*S+1 CTC states
#define NEGINF (-1e9f)
#define NORM_SCALE 32.0f
#define LOG2E 1.4426950408889634f
#define LN2   0.6931471805599453f

__device__ __forceinline__ float fexp2(float x) { return __builtin_amdgcn_exp2f(x); }
__device__ __forceinline__ float flog2(float x) { return __builtin_amdgcn_logf(x); }

// ---- col sum-of-squares of W (D x C), partial over d-chunks, atomic ----
__global__ void colnorm_kernel(const float* __restrict__ W, float* __restrict__ ssq) {
    int c = blockIdx.x * 64 + threadIdx.x;
    if (c >= CC) return;
    int d0 = blockIdx.y * 64;
    float ss = 0.f;
    #pragma unroll 8
    for (int d = d0; d < d0 + 64; ++d) {
        float v = W[(size_t)d * CC + c];
        ss += v * v;
    }
    atomicAdd(&ssq[c], ss);
}

// ---- build padded transposed normalized weight w_t (CP x DD), f16 ----
__global__ void wt_kernel(const float* __restrict__ W, const float* __restrict__ ssq,
                          f16* __restrict__ wt) {
    int idx = blockIdx.x * 256 + threadIdx.x;   // idx < CP*DD
    int c = idx >> 9, d = idx & 511;
    float v = 0.f;
    if (c < CC) v = W[(size_t)d * CC + c] * rsqrtf(ssq[c]);
    wt[idx] = (f16)v;
}

// ---- feats row-normalize -> f16 (one wave per row) ----
__global__ __launch_bounds__(256) void fnorm_kernel(const float* __restrict__ feats,
                                                    f16* __restrict__ fn) {
    int wv = (blockIdx.x * 256 + threadIdx.x) >> 6;  // row id, 0..16383
    int lane = threadIdx.x & 63;
    const float4* src = (const float4*)(feats + (size_t)wv * DD) + lane * 2;
    float4 a = src[0], b = src[1];
    float ss = a.x*a.x + a.y*a.y + a.z*a.z + a.w*a.w
             + b.x*b.x + b.y*b.y + b.z*b.z + b.w*b.w;
    #pragma unroll
    for (int off = 32; off; off >>= 1) ss += __shfl_xor(ss, off);
    float r = rsqrtf(ss);
    f16x8 o;
    o[0]=(f16)(a.x*r); o[1]=(f16)(a.y*r); o[2]=(f16)(a.z*r); o[3]=(f16)(a.w*r);
    o[4]=(f16)(b.x*r); o[5]=(f16)(b.y*r); o[6]=(f16)(b.z*r); o[7]=(f16)(b.w*r);
    *(f16x8*)(fn + (size_t)wv * DD + lane * 8) = o;
}

// ---- MFMA GEMM (A: 16384x512 f16, B^T: 1408x512 f16) with fused
//      row-wise sum(exp(32*dot)) epilogue -> atomicAdd into sumexp[16384] ----
__global__ __launch_bounds__(256) void gemm_sumexp_kernel(const f16* __restrict__ A,
                                                          const f16* __restrict__ B,
                                                          float* __restrict__ sumexp) {
    __shared__ __align__(16) f16 As[128 * 32];
    __shared__ __align__(16) f16 Bs[128 * 32];
    int bm = blockIdx.x, bn = blockIdx.y;
    int tid = threadIdx.x;
    int w = tid >> 6, lane = tid & 63;
    int wm = w >> 1, wn = w & 1;           // 2x2 wave grid -> 64x64 per wave
    int lm = lane & 15, hi = lane >> 4;
    f32x4 acc[4][4];
    f32x4 zero = {0.f, 0.f, 0.f, 0.f};
    #pragma unroll
    for (int i = 0; i < 4; ++i)
        #pragma unroll
        for (int j = 0; j < 4; ++j) acc[i][j] = zero;

    for (int kb = 0; kb < 16; ++kb) {      // K=512, BK=32 (one MFMA K-step)
        #pragma unroll
        for (int p = 0; p < 2; ++p) {
            int s = p * 256 + tid;         // segment id, 16B each; 512 segs/tile
            int row = s >> 2, ch = s & 3;
            const f16* ga = A + (size_t)(bm * 128 + row) * DD + kb * 32 + ch * 8;
            const f16* gb = B + (size_t)(bn * 128 + row) * DD + kb * 32 + ch * 8;
            // LDS dest = wave-uniform base + lane*16
            __builtin_amdgcn_global_load_lds((as1_void_ptr)ga,
                (as3_void_ptr)&As[(p * 256 + w * 64) * 8], 16, 0, 0);
            __builtin_amdgcn_global_load_lds((as1_void_ptr)gb,
                (as3_void_ptr)&Bs[(p * 256 + w * 64) * 8], 16, 0, 0);
        }
        __syncthreads();
        f16x8 af[4], bf[4];
        #pragma unroll
        for (int i = 0; i < 4; ++i)
            af[i] = *(const f16x8*)&As[(wm * 64 + i * 16 + lm) * 32 + hi * 8];
        #pragma unroll
        for (int j = 0; j < 4; ++j)
            bf[j] = *(const f16x8*)&Bs[(wn * 64 + j * 16 + lm) * 32 + hi * 8];
        #pragma unroll
        for (int i = 0; i < 4; ++i)
            #pragma unroll
            for (int j = 0; j < 4; ++j)
                acc[i][j] = __builtin_amdgcn_mfma_f32_16x16x32_f16(af[i], bf[j], acc[i][j], 0, 0, 0);
        __syncthreads();
    }
    // epilogue: per-row sum of exp(32*logit) over this block's 128 columns
    #pragma unroll
    for (int i = 0; i < 4; ++i) {
        float rs[4] = {0.f, 0.f, 0.f, 0.f};
        #pragma unroll
        for (int j = 0; j < 4; ++j) {
            int c = bn * 128 + wn * 64 + j * 16 + lm;   // C/D: col = lane&15
            bool ok = (c < CC);
            #pragma unroll
            for (int r = 0; r < 4; ++r)
                rs[r] += ok ? fexp2(acc[i][j][r] * (NORM_SCALE * LOG2E)) : 0.f;
        }
        #pragma unroll
        for (int off = 1; off < 16; off <<= 1) {        // sum over 16 cols
            #pragma unroll
            for (int r = 0; r < 4; ++r) rs[r] += __shfl_xor(rs[r], off);
        }
        if (lm == 0) {
            int rowb = bm * 128 + wm * 64 + i * 16 + hi * 4;  // row = quad*4+reg
            #pragma unroll
            for (int r = 0; r < 4; ++r) atomicAdd(&sumexp[rowb + r], rs[r]);
        }
    }
}

// ---- gather: lp_lab[n][j][t] = log2-prob of class slot j at (t,n) ----
__global__ __launch_bounds__(256) void gather_kernel(const f16* __restrict__ fn,
                                                     const f16* __restrict__ wt,
                                                     const float* __restrict__ sumexp,
                                                     const int* __restrict__ labels,
                                                     float* __restrict__ lp_lab) {
    int wv = (blockIdx.x * 256 + threadIdx.x) >> 6;  // row = t*32+n
    int lane = threadIdx.x & 63;
    int t = wv >> 5, n = wv & 31;
    f16x8 f8 = *(const f16x8*)(fn + (size_t)wv * DD + lane * 8);
    float fv[8];
    #pragma unroll
    for (int k = 0; k < 8; ++k) fv[k] = (float)f8[k];
    float lse2 = flog2(sumexp[wv]);   // log2(sum exp)
    float myval = 0.f;
    for (int j = 0; j < 31; ++j) {
        int cls = (j == 0) ? 0 : labels[n * SS + j - 1];
        f16x8 w8 = *(const f16x8*)(wt + (size_t)cls * DD + lane * 8);
        float d = 0.f;
        #pragma unroll
        for (int k = 0; k < 8; ++k) d += fv[k] * (float)w8[k];
        #pragma unroll
        for (int off = 32; off; off >>= 1) d += __shfl_xor(d, off);
        if (lane == j) myval = d;
    }
    if (lane < 31)   // base-2 log-prob, transposed layout: [n][j][t]
        lp_lab[((size_t)n * 31 + lane) * TT + t] =
            (NORM_SCALE * LOG2E) * myval - lse2;
}

// ---- CTC alpha recursion: one wave per sample, lane = state; base-2 ----
__global__ void ctc_kernel(const float* __restrict__ lp_lab, const int* __restrict__ labels,
                           const int* __restrict__ in_lens, const int* __restrict__ lab_lens,
                           float* __restrict__ nll) {
    int n = blockIdx.x;
    int s = threadIdx.x;     // 64 lanes; states 0..60 valid
    bool valid = s < LL;
    int ext = (valid && (s & 1)) ? labels[n * SS + (s >> 1)] : 0;
    int jmap = (valid && (s & 1)) ? ((s >> 1) + 1) : 0;   // state -> class slot
    int ext2 = __shfl_up(ext, 2);
    bool skip = (s >= 2) && valid && (ext != ext2);
    int Tin = in_lens[n];
    const float4* lp4 = (const float4*)(lp_lab + ((size_t)n * 31 + jmap) * TT);

    float4 cur = lp4[0];
    float4 nxt = lp4[1];
    float4 nx2 = lp4[2];
    float alpha = (s <= 1) ? cur.x : NEGINF;

    auto step = [&](int t, float lp) {
        float a1 = alpha;
        float a2 = __shfl_up(alpha, 1); if (s == 0) a2 = NEGINF;
        float a3 = __shfl_up(alpha, 2); if (!skip) a3 = NEGINF;
        float m = fmaxf(a1, fmaxf(a2, a3));
        float sum = fexp2(a1 - m) + fexp2(a2 - m) + fexp2(a3 - m);
        float nv = m + flog2(sum) + lp;
        if (t < Tin) alpha = nv;   // freeze past input length
    };

    // group 0: t = 1..3
    step(1, cur.y); step(2, cur.z); step(3, cur.w);
    for (int g = 1; g < 128; ++g) {
        cur = nxt; nxt = nx2;
        if (g + 2 < 128) nx2 = lp4[g + 2];   // 8-step prefetch window
        step(4 * g + 0, cur.x);
        step(4 * g + 1, cur.y);
        step(4 * g + 2, cur.z);
        step(4 * g + 3, cur.w);
    }

    int Ln = 2 * lab_lens[n] + 1;
    float last  = __shfl(alpha, Ln - 1);
    float last2 = __shfl(alpha, Ln - 2);
    float m2 = fmaxf(last, last2);
    float v = -(m2 + flog2(fexp2(last - m2) + fexp2(last2 - m2))) * LN2;
    if (s == 0) nll[n] = v;
}

__global__ void reduce_kernel(const float* __restrict__ nll, float* __restrict__ out) {
    int s = threadIdx.x;
    float v = (s < NN) ? nll[s] : 0.f;
    #pragma unroll
    for (int off = 32; off; off >>= 1) v += __shfl_xor(v, off);
    if (s == 0) out[0] = v;
}

extern "C" void kernel_launch(void* const* d_in, const int* in_sizes, int n_in,
                              void* d_out, int out_size, void* d_ws, size_t ws_size,
                              hipStream_t stream) {
    const float* feats        = (const float*)d_in[0];
    const float* W            = (const float*)d_in[1];
    const int*   labeling     = (const int*)d_in[2];
    const int*   logit_lgts   = (const int*)d_in[3];
    const int*   labeling_lgts= (const int*)d_in[4];
    float* out = (float*)d_out;
    char* ws = (char*)d_ws;

    size_t off = 0;
    f16*   wt     = (f16*)(ws + off);   off += (size_t)CP * DD * 2;        // 1.44 MB
    f16*   fn     = (f16*)(ws + off);   off += (size_t)TT * NN * DD * 2;   // 16.8 MB
    float* ssq    = (float*)(ws + off); off += 1312 * 4;
    float* sumexp = (float*)(ws + off); off += (size_t)TT * NN * 4;        // 64 KB
    float* lp_lab = (float*)(ws + off); off += (size_t)NN * 31 * TT * 4;   // 2.0 MB
    float* nllb   = (float*)(ws + off); off += 64 * 4;

    hipMemsetAsync(ssq, 0, 1312 * 4, stream);
    hipMemsetAsync(sumexp, 0, (size_t)TT * NN * 4, stream);

    colnorm_kernel<<<dim3((CC + 63) / 64, 8), 64, 0, stream>>>(W, ssq);
    wt_kernel<<<(CP * DD) / 256, 256, 0, stream>>>(W, ssq, wt);
    fnorm_kernel<<<(TT * NN) / 4, 256, 0, stream>>>(feats, fn);
    gemm_sumexp_kernel<<<dim3(TT * NN / 128, CP / 128), 256, 0, stream>>>(fn, wt, sumexp);
    gather_kernel<<<(TT * NN) / 4, 256, 0, stream>>>(fn, wt, sumexp, labeling, lp_lab);
    ctc_kernel<<<NN, 64, 0, stream>>>(lp_lab, labeling, logit_lgts, labeling_lgts, nllb);
    reduce_kernel<<<1, 64, 0, stream>>>(nllb, out);

    (void)in_sizes; (void)n_in; (void)out_size; (void)ws_size;
}

// Round 4
// 177.319 us; speedup vs baseline: 1.3851x; 1.1556x over previous
//
#include <hip/hip_runtime.h>
#include <stdint.h>
#include <stddef.h>

// RadialCTC: cosine logits (norm_scale=32) -> log_softmax -> CTC(sum).
// Strategy: never materialize the (16384 x 1296) logits. GEMM (f16 MFMA)
// computes per-row sum(exp(logit)) fused in the epilogue (no max needed:
// logits in [-32,32]); label log-probs via a small MFMA gather-GEMM
// (per sample: 512 t's x 31 classes x 512, label weights staged once in
// LDS); CTC alpha recursion one wave per sample, shfl_up, base-2.
// R2: lp_lab [n][31][T], float4 feed, base-2 via __builtin_amdgcn_exp2f/_logf.
// R4: gather rewritten from per-j 64-lane butterfly (44us, VALU-bound) to
//     MFMA (Guideline 10: matmul-shaped compute belongs on matrix cores).

typedef _Float16 f16;
typedef _Float16 f16x8 __attribute__((ext_vector_type(8)));
typedef float f32x4 __attribute__((ext_vector_type(4)));
typedef __attribute__((address_space(1))) void* as1_void_ptr;
typedef __attribute__((address_space(3))) void* as3_void_ptr;

#define TT 512
#define NN 32
#define CC 1296
#define DD 512
#define SS 30
#define CP 1408   // C padded to 11*128 for GEMM tiling (pad rows are zero)
#define LL 61     // 2*S+1 CTC states
#define NEGINF (-1e9f)
#define NORM_SCALE 32.0f
#define LOG2E 1.4426950408889634f
#define LN2   0.6931471805599453f

__device__ __forceinline__ float fexp2(float x) { return __builtin_amdgcn_exp2f(x); }
__device__ __forceinline__ float flog2(float x) { return __builtin_amdgcn_logf(x); }

// ---- col sum-of-squares of W (D x C), partial over d-chunks, atomic ----
__global__ void colnorm_kernel(const float* __restrict__ W, float* __restrict__ ssq) {
    int c = blockIdx.x * 64 + threadIdx.x;
    if (c >= CC) return;
    int d0 = blockIdx.y * 64;
    float ss = 0.f;
    #pragma unroll 8
    for (int d = d0; d < d0 + 64; ++d) {
        float v = W[(size_t)d * CC + c];
        ss += v * v;
    }
    atomicAdd(&ssq[c], ss);
}

// ---- build padded transposed normalized weight w_t (CP x DD), f16 ----
__global__ void wt_kernel(const float* __restrict__ W, const float* __restrict__ ssq,
                          f16* __restrict__ wt) {
    int idx = blockIdx.x * 256 + threadIdx.x;   // idx < CP*DD
    int c = idx >> 9, d = idx & 511;
    float v = 0.f;
    if (c < CC) v = W[(size_t)d * CC + c] * rsqrtf(ssq[c]);
    wt[idx] = (f16)v;
}

// ---- feats row-normalize -> f16 (one wave per row) ----
__global__ __launch_bounds__(256) void fnorm_kernel(const float* __restrict__ feats,
                                                    f16* __restrict__ fn) {
    int wv = (blockIdx.x * 256 + threadIdx.x) >> 6;  // row id, 0..16383
    int lane = threadIdx.x & 63;
    const float4* src = (const float4*)(feats + (size_t)wv * DD) + lane * 2;
    float4 a = src[0], b = src[1];
    float ss = a.x*a.x + a.y*a.y + a.z*a.z + a.w*a.w
             + b.x*b.x + b.y*b.y + b.z*b.z + b.w*b.w;
    #pragma unroll
    for (int off = 32; off; off >>= 1) ss += __shfl_xor(ss, off);
    float r = rsqrtf(ss);
    f16x8 o;
    o[0]=(f16)(a.x*r); o[1]=(f16)(a.y*r); o[2]=(f16)(a.z*r); o[3]=(f16)(a.w*r);
    o[4]=(f16)(b.x*r); o[5]=(f16)(b.y*r); o[6]=(f16)(b.z*r); o[7]=(f16)(b.w*r);
    *(f16x8*)(fn + (size_t)wv * DD + lane * 8) = o;
}

// ---- MFMA GEMM (A: 16384x512 f16, B^T: 1408x512 f16) with fused
//      row-wise sum(exp(32*dot)) epilogue -> atomicAdd into sumexp[16384] ----
__global__ __launch_bounds__(256) void gemm_sumexp_kernel(const f16* __restrict__ A,
                                                          const f16* __restrict__ B,
                                                          float* __restrict__ sumexp) {
    __shared__ __align__(16) f16 As[128 * 32];
    __shared__ __align__(16) f16 Bs[128 * 32];
    int bm = blockIdx.x, bn = blockIdx.y;
    int tid = threadIdx.x;
    int w = tid >> 6, lane = tid & 63;
    int wm = w >> 1, wn = w & 1;           // 2x2 wave grid -> 64x64 per wave
    int lm = lane & 15, hi = lane >> 4;
    f32x4 acc[4][4];
    f32x4 zero = {0.f, 0.f, 0.f, 0.f};
    #pragma unroll
    for (int i = 0; i < 4; ++i)
        #pragma unroll
        for (int j = 0; j < 4; ++j) acc[i][j] = zero;

    for (int kb = 0; kb < 16; ++kb) {      // K=512, BK=32 (one MFMA K-step)
        #pragma unroll
        for (int p = 0; p < 2; ++p) {
            int s = p * 256 + tid;         // segment id, 16B each; 512 segs/tile
            int row = s >> 2, ch = s & 3;
            const f16* ga = A + (size_t)(bm * 128 + row) * DD + kb * 32 + ch * 8;
            const f16* gb = B + (size_t)(bn * 128 + row) * DD + kb * 32 + ch * 8;
            // LDS dest = wave-uniform base + lane*16
            __builtin_amdgcn_global_load_lds((as1_void_ptr)ga,
                (as3_void_ptr)&As[(p * 256 + w * 64) * 8], 16, 0, 0);
            __builtin_amdgcn_global_load_lds((as1_void_ptr)gb,
                (as3_void_ptr)&Bs[(p * 256 + w * 64) * 8], 16, 0, 0);
        }
        __syncthreads();
        f16x8 af[4], bf[4];
        #pragma unroll
        for (int i = 0; i < 4; ++i)
            af[i] = *(const f16x8*)&As[(wm * 64 + i * 16 + lm) * 32 + hi * 8];
        #pragma unroll
        for (int j = 0; j < 4; ++j)
            bf[j] = *(const f16x8*)&Bs[(wn * 64 + j * 16 + lm) * 32 + hi * 8];
        #pragma unroll
        for (int i = 0; i < 4; ++i)
            #pragma unroll
            for (int j = 0; j < 4; ++j)
                acc[i][j] = __builtin_amdgcn_mfma_f32_16x16x32_f16(af[i], bf[j], acc[i][j], 0, 0, 0);
        __syncthreads();
    }
    // epilogue: per-row sum of exp(32*logit) over this block's 128 columns
    #pragma unroll
    for (int i = 0; i < 4; ++i) {
        float rs[4] = {0.f, 0.f, 0.f, 0.f};
        #pragma unroll
        for (int j = 0; j < 4; ++j) {
            int c = bn * 128 + wn * 64 + j * 16 + lm;   // C/D: col = lane&15
            bool ok = (c < CC);
            #pragma unroll
            for (int r = 0; r < 4; ++r)
                rs[r] += ok ? fexp2(acc[i][j][r] * (NORM_SCALE * LOG2E)) : 0.f;
        }
        #pragma unroll
        for (int off = 1; off < 16; off <<= 1) {        // sum over 16 cols
            #pragma unroll
            for (int r = 0; r < 4; ++r) rs[r] += __shfl_xor(rs[r], off);
        }
        if (lm == 0) {
            int rowb = bm * 128 + wm * 64 + i * 16 + hi * 4;  // row = quad*4+reg
            #pragma unroll
            for (int r = 0; r < 4; ++r) atomicAdd(&sumexp[rowb + r], rs[r]);
        }
    }
}

// ---- gather-GEMM: per (n, 64-t chunk), P = Fn(64x512) x Wlab^T(32x512),
//      lp_lab[n][j][t] = 32*log2e*P - log2(sumexp).  Label weights (32 rows,
//      padded; row 0 = blank, 1..30 = labels, 31 = dup blank) staged ONCE
//      in LDS, tiled [kb][row][32] like As. ----
__global__ __launch_bounds__(256) void gather_kernel(const f16* __restrict__ fn,
                                                     const f16* __restrict__ wt,
                                                     const float* __restrict__ sumexp,
                                                     const int* __restrict__ labels,
                                                     float* __restrict__ lp_lab) {
    __shared__ __align__(16) f16 Bs[16 * 32 * 32];   // 32 KB: [kb][row][kk]
    __shared__ __align__(16) f16 As[64 * 32];        // 4 KB
    __shared__ float ls2[64];
    int n = blockIdx.x, t0 = blockIdx.y * 64;
    int tid = threadIdx.x;
    int w = tid >> 6, lane = tid & 63;
    int lm = lane & 15, hi = lane >> 4;

    // stage whole label-weight tile: 2048 segs of 16B, 8 iters
    #pragma unroll
    for (int it = 0; it < 8; ++it) {
        int s = it * 256 + tid;                // kb = s>>7, row = (s>>2)&31, ch = s&3
        int row = (s >> 2) & 31;
        int cls = (row == 0 || row > SS) ? 0 : labels[n * SS + row - 1];
        const f16* gb = wt + (size_t)cls * DD + (s >> 7) * 32 + (s & 3) * 8;
        __builtin_amdgcn_global_load_lds((as1_void_ptr)gb,
            (as3_void_ptr)&Bs[(it * 256 + w * 64) * 8], 16, 0, 0);
    }
    if (tid < 64) ls2[tid] = flog2(sumexp[(size_t)(t0 + tid) * NN + n]);

    f32x4 acc[2];
    acc[0] = (f32x4){0.f, 0.f, 0.f, 0.f};
    acc[1] = (f32x4){0.f, 0.f, 0.f, 0.f};
    for (int kb = 0; kb < 16; ++kb) {
        int row = tid >> 2, ch = tid & 3;      // 256 segs: 64 rows x 4 ch
        const f16* ga = fn + (size_t)((t0 + row) * NN + n) * DD + kb * 32 + ch * 8;
        __builtin_amdgcn_global_load_lds((as1_void_ptr)ga,
            (as3_void_ptr)&As[(w * 64) * 8], 16, 0, 0);
        __syncthreads();                       // also covers Bs/ls2 on kb==0
        f16x8 af = *(const f16x8*)&As[(w * 16 + lm) * 32 + hi * 8];
        f16x8 bf0 = *(const f16x8*)&Bs[kb * 1024 + lm * 32 + hi * 8];
        f16x8 bf1 = *(const f16x8*)&Bs[kb * 1024 + (16 + lm) * 32 + hi * 8];
        acc[0] = __builtin_amdgcn_mfma_f32_16x16x32_f16(af, bf0, acc[0], 0, 0, 0);
        acc[1] = __builtin_amdgcn_mfma_f32_16x16x32_f16(af, bf1, acc[1], 0, 0, 0);
        __syncthreads();
    }
    // epilogue: C/D col=lane&15 (class slot), row=quad*4+reg (t within tile)
    #pragma unroll
    for (int jn = 0; jn < 2; ++jn) {
        int j = jn * 16 + lm;
        if (j >= 31) continue;
        float* dst = lp_lab + ((size_t)n * 31 + j) * TT + t0;
        #pragma unroll
        for (int r = 0; r < 4; ++r) {
            int tl = w * 16 + hi * 4 + r;
            dst[tl] = acc[jn][r] * (NORM_SCALE * LOG2E) - ls2[tl];
        }
    }
}

// ---- CTC alpha recursion: one wave per sample, lane = state; base-2 ----
__global__ void ctc_kernel(const float* __restrict__ lp_lab, const int* __restrict__ labels,
                           const int* __restrict__ in_lens, const int* __restrict__ lab_lens,
                           float* __restrict__ nll) {
    int n = blockIdx.x;
    int s = threadIdx.x;     // 64 lanes; states 0..60 valid
    bool valid = s < LL;
    int ext = (valid && (s & 1)) ? labels[n * SS + (s >> 1)] : 0;
    int jmap = (valid && (s & 1)) ? ((s >> 1) + 1) : 0;   // state -> class slot
    int ext2 = __shfl_up(ext, 2);
    bool skip = (s >= 2) && valid && (ext != ext2);
    int Tin = in_lens[n];
    const float4* lp4 = (const float4*)(lp_lab + ((size_t)n * 31 + jmap) * TT);

    float4 cur = lp4[0];
    float4 nxt = lp4[1];
    float4 nx2 = lp4[2];
    float alpha = (s <= 1) ? cur.x : NEGINF;

    auto step = [&](int t, float lp) {
        float a1 = alpha;
        float a2 = __shfl_up(alpha, 1); if (s == 0) a2 = NEGINF;
        float a3 = __shfl_up(alpha, 2); if (!skip) a3 = NEGINF;
        float m = fmaxf(a1, fmaxf(a2, a3));
        float sum = fexp2(a1 - m) + fexp2(a2 - m) + fexp2(a3 - m);
        float nv = m + flog2(sum) + lp;
        if (t < Tin) alpha = nv;   // freeze past input length
    };

    // group 0: t = 1..3
    step(1, cur.y); step(2, cur.z); step(3, cur.w);
    for (int g = 1; g < 128; ++g) {
        cur = nxt; nxt = nx2;
        if (g + 2 < 128) nx2 = lp4[g + 2];   // 8-step prefetch window
        step(4 * g + 0, cur.x);
        step(4 * g + 1, cur.y);
        step(4 * g + 2, cur.z);
        step(4 * g + 3, cur.w);
    }

    int Ln = 2 * lab_lens[n] + 1;
    float last  = __shfl(alpha, Ln - 1);
    float last2 = __shfl(alpha, Ln - 2);
    float m2 = fmaxf(last, last2);
    float v = -(m2 + flog2(fexp2(last - m2) + fexp2(last2 - m2))) * LN2;
    if (s == 0) nll[n] = v;
}

__global__ void reduce_kernel(const float* __restrict__ nll, float* __restrict__ out) {
    int s = threadIdx.x;
    float v = (s < NN) ? nll[s] : 0.f;
    #pragma unroll
    for (int off = 32; off; off >>= 1) v += __shfl_xor(v, off);
    if (s == 0) out[0] = v;
}

extern "C" void kernel_launch(void* const* d_in, const int* in_sizes, int n_in,
                              void* d_out, int out_size, void* d_ws, size_t ws_size,
                              hipStream_t stream) {
    const float* feats        = (const float*)d_in[0];
    const float* W            = (const float*)d_in[1];
    const int*   labeling     = (const int*)d_in[2];
    const int*   logit_lgts   = (const int*)d_in[3];
    const int*   labeling_lgts= (const int*)d_in[4];
    float* out = (float*)d_out;
    char* ws = (char*)d_ws;

    size_t off = 0;
    f16*   wt     = (f16*)(ws + off);   off += (size_t)CP * DD * 2;        // 1.44 MB
    f16*   fn     = (f16*)(ws + off);   off += (size_t)TT * NN * DD * 2;   // 16.8 MB
    float* ssq    = (float*)(ws + off); off += 1312 * 4;
    float* sumexp = (float*)(ws + off); off += (size_t)TT * NN * 4;        // 64 KB
    float* lp_lab = (float*)(ws + off); off += (size_t)NN * 31 * TT * 4;   // 2.0 MB
    float* nllb   = (float*)(ws + off); off += 64 * 4;

    hipMemsetAsync(ssq, 0, 1312 * 4, stream);
    hipMemsetAsync(sumexp, 0, (size_t)TT * NN * 4, stream);

    colnorm_kernel<<<dim3((CC + 63) / 64, 8), 64, 0, stream>>>(W, ssq);
    wt_kernel<<<(CP * DD) / 256, 256, 0, stream>>>(W, ssq, wt);
    fnorm_kernel<<<(TT * NN) / 4, 256, 0, stream>>>(feats, fn);
    gemm_sumexp_kernel<<<dim3(TT * NN / 128, CP / 128), 256, 0, stream>>>(fn, wt, sumexp);
    gather_kernel<<<dim3(NN, TT / 64), 256, 0, stream>>>(fn, wt, sumexp, labeling, lp_lab);
    ctc_kernel<<<NN, 64, 0, stream>>>(lp_lab, labeling, logit_lgts, labeling_lgts, nllb);
    reduce_kernel<<<1, 64, 0, stream>>>(nllb, out);

    (void)in_sizes; (void)n_in; (void)out_size; (void)ws_size;
}